// Round 17
// baseline (105.813 us; speedup 1.0000x reference)
//
#include <hip/hip_runtime.h>
#include <stdint.h>

// Problem constants (fixed by setup_inputs): B=32, N=512, D=512
#define BATCH 32
#define NDIM 512
#define DDIM 512
#define XELEMS (BATCH * NDIM * DDIM)   // 8388608

typedef _Float16 f16x8 __attribute__((ext_vector_type(8)));
typedef float f32x4 __attribute__((ext_vector_type(4)));

__device__ __forceinline__ f16x8 cvt8(float4 u0, float4 u1) {
    f16x8 r;
    r[0] = (_Float16)u0.x; r[1] = (_Float16)u0.y;
    r[2] = (_Float16)u0.z; r[3] = (_Float16)u0.w;
    r[4] = (_Float16)u1.x; r[5] = (_Float16)u1.y;
    r[6] = (_Float16)u1.z; r[7] = (_Float16)u1.w;
    return r;
}

// ===================================================================================
// [R15/R16 — REGISTER-DIRECT B FROM THE TILED LAYOUT (R16 = resubmit after infra
//  failure; kernel never executed). R14 ran: passed, 105.6 µs total (banked best).
//  Inferred fused ≈ 35-37 µs -> hit the pre-committed falsifier band: transaction
//  contiguity was NOT the dominant residual. Surviving hypothesis: the per-iter
//  machinery (gl_lds issue + manual WAITVM serialization) + the B LDS round-trip
//  for ZERO-REUSE wave-private strips (Common-mistake #7, kept since R5). LDS pipe:
//  8 waves x 8 ds_read_b128 x 12cy = 768 cy/CU/iter vs 160 cy MFMA — the B half of
//  those reads is avoidable. R8 tried register-direct B and LOST — explained: old
//  row-major layout made fragments 16-line strided. With R14's tiled chunks, a
//  wave's B-fragment load = 64 lanes x 16B covering ONE contiguous 1KB chunk
//  (lane-permuted) -> fully coalesced. The layout unlocks the R8 idea.
//  This kernel: NO Bs LDS, NO gl_lds, NO inline asm. B = depth-2 register pipeline
//  of plain coalesced loads (compiler scoreboard = counted vmcnt for free). A staged
//  once via reg->ds_write (8KB/wave); 3 plain __syncthreads; zero in-loop sync.
//  LDS = AY 64KB. Fragment/K-order math bit-identical to R1/R5/R14 (all HW-passed;
//  R16 audit: register-direct reads fetch byte-identical elements to R14's
//  Bs-staged reads — LDS hop removed, value path unchanged; wave B-read = 64 x 16B
//  covering exactly one 1KB chunk).
//  Predictions: fused 36 -> 20-26 µs, total 92-99; conflicts ~halve (a-reads only);
//  VGPR 120-180, localMem 0. Falsifier: total >= 103 -> re-bank R14 verbatim.]
// ===================================================================================

// ---------------- pass 0: build Xh_t (fp32->fp16, tiled+swizzled) and Wt_t ---------
// (unchanged from R14 — harness-verified in the R15 round)
__global__ __launch_bounds__(256) void prep(const float* __restrict__ X,
                                            _Float16* __restrict__ XhT,
                                            const float* __restrict__ W,
                                            _Float16* __restrict__ WtT) {
    int bid = blockIdx.x;
    if (bid < 4096) {
        // X part: 16384 groups (b,kt,ch), 4 per block; wave-contiguous 1KB writes.
        int g    = bid * 4 + (threadIdx.x >> 6);
        int lane = threadIdx.x & 63;
        int b  = g >> 9;             // 0..31
        int kt = (g >> 5) & 15;      // 0..15
        int ch = g & 31;             // 0..31
        int r = lane >> 2, s = lane & 3;
        int col = kt * 32 + ((s ^ ((r >> 1) & 3)) << 3);   // pre-swizzled source col
        const float* src = X + ((size_t)(b * 512 + ch * 16 + r)) * DDIM + col;
        float4 u0 = *(const float4*)src;
        float4 u1 = *(const float4*)(src + 4);
        *(f16x8*)&XhT[(size_t)g * 512 + lane * 8] = cvt8(u0, u1);
    } else {
        // W part: 256 tiles of 32x32; LDS transpose then tiled-swizzled 16B writes.
        __shared__ float tile[32][33];
        int t  = bid - 4096;
        int bx = t & 15;             // e-tile
        int by = t >> 4;             // d-tile == kt
        int tx = threadIdx.x & 31;
        int ty = threadIdx.x >> 5;   // 0..7
        for (int rr = ty; rr < 32; rr += 8)
            tile[rr][tx] = W[(by * 32 + rr) * DDIM + bx * 32 + tx];
        __syncthreads();
        int idx = threadIdx.x;       // threads 0..127 write one 16B slot each
        if (idx < 128) {
            int er = idx >> 2;                  // e-within 0..31
            int sp = idx & 3;                   // physical slot
            int rr = er & 15;                   // r within chunk
            int sl = sp ^ ((rr >> 1) & 3);      // logical slot
            f16x8 v;
#pragma unroll
            for (int j = 0; j < 8; ++j)
                v[j] = (_Float16)tile[sl * 8 + j][er];
            int ch = bx * 2 + (er >> 4);
            *(f16x8*)&WtT[((size_t)(by * 32 + ch)) * 512 + rr * 32 + sp * 8] = v;
        }
    }
}

// ---------------- fused: S_b = (X_b @ W) @ X_b^T + bias, diag = 0 -------------------
// Grid: 256 blocks = rslice*32 + batch (blk%8 = batch%8 -> one batch's 8 row-slice
// blocks share an XCD; X_bT (0.5MB) and WtT (0.5MB) L2-resident per XCD).
__global__ __launch_bounds__(512, 2) void fused(const _Float16* __restrict__ XhT,
                                                const _Float16* __restrict__ WtT,
                                                float* __restrict__ Sout,
                                                const float* __restrict__ bias_ptr) {
    // AY: phase 1 = A-chunks [16 kt][4 rc][16 r][32 col] fp16; then Ylds[64][512].
    __shared__ __align__(16) _Float16 AY[64 * 512];        // 64 KB (only LDS)

    const int tid  = threadIdx.x;
    const int lane = tid & 63;
    const int wv   = tid >> 6;        // 0..7
    const int quad = lane >> 4;       // 0..3
    const int l16  = lane & 15;

    // fragment read slot (read side of the layout-baked involution)
    const int paK = (quad ^ ((l16 >> 1) & 3)) * 8;
    const int fro = l16 * 32 + paK;   // fragment offset within a 512-fp16 chunk

    const int blk   = blockIdx.x;     // 256 blocks
    const int batch = blk & 31;
    const int r0    = (blk >> 5) * 64;
    const int ch0   = r0 >> 4;        // first A row-chunk

    const _Float16* Xt = XhT + (size_t)(batch * 16) * 32 * 512;  // batch's kt-tiles

    f32x4 acc[4][4];
#pragma unroll
    for (int i = 0; i < 4; ++i)
#pragma unroll
        for (int j = 0; j < 4; ++j)
            acc[i][j] = (f32x4){0.f, 0.f, 0.f, 0.f};

    // ---- prologue: A reg-stage into LDS (8 chunks/wave, 1KB sequential each).
#pragma unroll
    for (int c = 0; c < 8; ++c) {
        const int kt = wv * 2 + (c >> 2);         // k-tile (2 per wave)
        const int rc = c & 3;                     // row-chunk 0..3
        f16x8 v = *(const f16x8*)&Xt[((size_t)(kt * 32 + ch0 + rc)) * 512 + lane * 8];
        *(f16x8*)&AY[(kt * 4 + rc) * 512 + lane * 8] = v;
    }
    __syncthreads();                  // A visible to all waves

    // ---- phase-1 B prefetch: depth-2 register pipeline (coalesced 1KB chunks).
    f16x8 bb[2][4];
#pragma unroll
    for (int d = 0; d < 2; ++d)
#pragma unroll
        for (int nt = 0; nt < 4; ++nt)
            bb[d][nt] = *(const f16x8*)&WtT[((size_t)(d * 32 + wv * 4 + nt)) * 512 + fro];

    // ================= phase 1: Y = X_b[r0:r0+64][:] @ Wt^T  (16 iters, BK=32) =====
    // No barriers, no LDS for B; scoreboard waits only tile it's registers.
#pragma unroll
    for (int it = 0; it < 16; ++it) {
        const int s = it & 1;                     // compile-time after unroll
        f16x8 bcur[4];
#pragma unroll
        for (int nt = 0; nt < 4; ++nt)
            bcur[nt] = bb[s][nt];
        if (it + 2 < 16) {
#pragma unroll
            for (int nt = 0; nt < 4; ++nt)
                bb[s][nt] = *(const f16x8*)&WtT[((size_t)((it + 2) * 32 + wv * 4 + nt)) * 512 + fro];
        }
        f16x8 a[4];
#pragma unroll
        for (int mt = 0; mt < 4; ++mt)
            a[mt] = *(const f16x8*)&AY[(it * 4 + mt) * 512 + fro];
#pragma unroll
        for (int mt = 0; mt < 4; ++mt)
#pragma unroll
            for (int nt = 0; nt < 4; ++nt)
                acc[mt][nt] = __builtin_amdgcn_mfma_f32_16x16x32_f16(
                    a[mt], bcur[nt], acc[mt][nt], 0, 0, 0);
    }

    // ---- interphase: Y -> AY as Ylds (e-chunk XOR-swizzled; C/D col=l16,
    // row=quad*4+r, m89-verified — unchanged from R14).
    __syncthreads();                  // all waves' phase-1 AY reads complete
#pragma unroll
    for (int mt = 0; mt < 4; ++mt)
#pragma unroll
        for (int nt = 0; nt < 4; ++nt)
#pragma unroll
            for (int r = 0; r < 4; ++r) {
                int i = mt * 16 + quad * 4 + r;        // Y row (0..63)
                int e = wv * 64 + nt * 16 + l16;       // Y col (0..511)
                int c = e >> 3, j = e & 7;
                AY[i * 512 + (((c ^ (i & 7)) << 3) | j)] = (_Float16)acc[mt][nt][r];
            }
    __syncthreads();                  // Ylds visible (incl. lgkm drain)

    // ================= phase 2: S = Y @ X_b^T  (16 iters, BK=32, barrier-free) =====
#pragma unroll
    for (int i = 0; i < 4; ++i)
#pragma unroll
        for (int j = 0; j < 4; ++j)
            acc[i][j] = (f32x4){0.f, 0.f, 0.f, 0.f};

    f16x8 cb[2][4];                   // phase-2 depth-2 pipeline (X_b tiled chunks)
#pragma unroll
    for (int d = 0; d < 2; ++d)
#pragma unroll
        for (int nt = 0; nt < 4; ++nt)
            cb[d][nt] = *(const f16x8*)&Xt[((size_t)(d * 32 + wv * 4 + nt)) * 512 + fro];

#pragma unroll
    for (int it = 0; it < 16; ++it) {
        const int s = it & 1;
        f16x8 bcur[4];
#pragma unroll
        for (int nt = 0; nt < 4; ++nt)
            bcur[nt] = cb[s][nt];
        if (it + 2 < 16) {
#pragma unroll
            for (int nt = 0; nt < 4; ++nt)
                cb[s][nt] = *(const f16x8*)&Xt[((size_t)((it + 2) * 32 + wv * 4 + nt)) * 512 + fro];
        }
        const int pay = (((it * 4 + quad) ^ (l16 & 7)) * 8);  // Ylds swizzled col
        f16x8 a[4];
#pragma unroll
        for (int mt = 0; mt < 4; ++mt)
            a[mt] = *(const f16x8*)&AY[(mt * 16 + l16) * 512 + pay];
#pragma unroll
        for (int mt = 0; mt < 4; ++mt)
#pragma unroll
            for (int nt = 0; nt < 4; ++nt)
                acc[mt][nt] = __builtin_amdgcn_mfma_f32_16x16x32_f16(
                    a[mt], bcur[nt], acc[mt][nt], 0, 0, 0);
    }

    // ---- epilogue: bias, zero diagonal, fp32 store
    const float bias = bias_ptr[0];
#pragma unroll
    for (int mt = 0; mt < 4; ++mt)
#pragma unroll
        for (int nt = 0; nt < 4; ++nt)
#pragma unroll
            for (int r = 0; r < 4; ++r) {
                int gi = r0 + mt * 16 + quad * 4 + r;   // row within batch (0..511)
                int gj = wv * 64 + nt * 16 + l16;       // col within batch (0..511)
                float v = acc[mt][nt][r] + bias;
                if (gi == gj) v = 0.f;
                Sout[((size_t)batch * NDIM + gi) * NDIM + gj] = v;
            }
}

extern "C" void kernel_launch(void* const* d_in, const int* in_sizes, int n_in,
                              void* d_out, int out_size, void* d_ws, size_t ws_size,
                              hipStream_t stream) {
    const float* X  = (const float*)d_in[0];   // (32, 512, 512) fp32
    const float* W  = (const float*)d_in[1];   // (512, 512) fp32
    const float* bp = (const float*)d_in[2];   // scalar fp32
    float* out = (float*)d_out;                // (32, 512, 512) fp32

    // workspace (fp16): XhT[8388608] | WtT[262144]
    _Float16* XhT = (_Float16*)d_ws;
    _Float16* WtT = XhT + XELEMS;

    // pass 0: tiled+swizzled fp16 layouts (4096 X-blocks + 256 W-blocks)
    prep<<<4096 + 256, 256, 0, stream>>>(X, XhT, W, WtT);

    // fused: A staged once into LDS; B register-direct (coalesced tiled chunks,
    // depth-2 reg pipeline); Ylds reuses A's LDS; 3 barriers, no inline asm.
    fused<<<256, 512, 0, stream>>>(XhT, WtT, out, bp);

    (void)in_sizes; (void)n_in; (void)out_size; (void)ws_size;
}